// Round 11
// baseline (128.806 us; speedup 1.0000x reference)
//
#include <hip/hip_runtime.h>
#include <hip/hip_bf16.h>
#include <math.h>

// Laplacian-pyramid L1 loss, (2,1,64,256,256), 5 levels, sigma=1 (9-tap), scipy-reflect.
// loss = sum_l mean |lap_pyramid(input-target)[l]| (linearity of the pyramid).
// 8 plain launches (kernel boundaries are the only cheap dependency mechanism;
// r5/r7: no cross-block sync):
//  D1 k1l0(+bf16 DIFF x<132 + x>=132 partials)
//  D2 M1 (z-down+mix of T1 -> C1, fused XY-down -> Tl1)
//  D3 M2 || k3(0)->V0
//  D4 M3 || k3(1)->V1 || k4-L0
//  D5 M4 || k3(2)->V2 || k4-L1
//  D6 M5(C5 only) || k4-L2
//  D7 k4-L3 || k4-L4
//  D8 kreduce

struct GW { float w[9]; float A, B; };

__device__ __forceinline__ int ridx(int p, int n) {
    // scipy 'reflect' (symmetric) for power-of-two n; valid for p >= -2n
    int m = 2 * n;
    int q = (p + m) & (m - 1);
    return (q < n) ? q : (m - 1 - q);
}

__device__ __forceinline__ float block_sum256(float v) {
    #pragma unroll
    for (int off = 32; off > 0; off >>= 1) v += __shfl_down(v, off, 64);
    __shared__ float wp[4];
    int tid = threadIdx.x;
    if ((tid & 63) == 0) wp[tid >> 6] = v;
    __syncthreads();
    return wp[0] + wp[1] + wp[2] + wp[3];
}

// ---------------------------------------------------------------------------
// k1l0: level-0 fused W+H gaussian of (in - tg) -> T1 (even y,x).
// Also: bf16 DIFF for x<132, and the x>=132 |diff| sums as partials P[0..1024).
template<bool WDIFF>
__global__ __launch_bounds__(256)
void k1l0(const float* __restrict__ in, const float* __restrict__ tg,
          float* __restrict__ T1, __hip_bfloat16* __restrict__ DIFF,
          float* __restrict__ P, GW g)
{
    const int H = 256, W = 256, Wd = 128;
    const int x0d = blockIdx.x * 64, y0d = blockIdx.y * 16, slice = blockIdx.z;
    __shared__ float raw[40][136];
    __shared__ float mid[40][64];
    const size_t in_off  = (size_t)slice * H * W;
    const size_t out_off = (size_t)slice * 128 * 128;
    const int tid = threadIdx.x;
    const int gy0 = 2*y0d - 4, gx0 = 2*x0d - 4;
    for (int i = tid; i < 40*32; i += 256) {
        int rr = i >> 5, c4 = (i & 31) + 1;
        int gy = ridx(gy0 + rr, H);
        size_t base = in_off + (size_t)gy * W + gx0 + 4*c4;
        float4 v = *(const float4*)(in + base);
        float4 b = *(const float4*)(tg + base);
        v.x -= b.x; v.y -= b.y; v.z -= b.z; v.w -= b.w;
        *(float4*)&raw[rr][4*c4] = v;
    }
    for (int i = tid; i < 40*8; i += 256) {
        int rr = i >> 3, j = i & 7;
        int cc = (j < 4) ? j : (128 + j);
        int gy = ridx(gy0 + rr, H);
        int gx = ridx(gx0 + cc, W);
        size_t idx = in_off + (size_t)gy * W + gx;
        raw[rr][cc] = in[idx] - tg[idx];
    }
    __syncthreads();
    if (WDIFF) {
        if (blockIdx.x == 0) {
            for (int i = tid; i < 32*128; i += 256) {
                int r = i >> 7, c = i & 127;
                DIFF[in_off + (size_t)(2*y0d + r) * W + c] =
                    __float2bfloat16(raw[4 + r][4 + c]);
            }
        } else {
            for (int i = tid; i < 32*4; i += 256) {
                int r = i >> 2, c = i & 3;
                DIFF[in_off + (size_t)(2*y0d + r) * W + 128 + c] =
                    __float2bfloat16(raw[4 + r][4 + c]);
            }
        }
    }
    if (blockIdx.x == 1) {
        // x >= 132 loss contribution (up == 0 there)
        float lsum = 0.f;
        for (int i = tid; i < 32*124; i += 256) {
            int r = i / 124, c = i - r*124;
            lsum += fabsf(raw[4 + r][8 + c]);
        }
        float tot = block_sum256(lsum);
        if (tid == 0)
            P[blockIdx.y + 8*blockIdx.z] = tot * (1.f / 8388608.f);
    }
    for (int i = tid; i < 40*64; i += 256) {
        int rr = i >> 6, c = i & 63;
        float s = 0.f;
        #pragma unroll
        for (int k = 0; k < 9; ++k) s = fmaf(g.w[k], raw[rr][2*c + k], s);
        mid[rr][c] = s;
    }
    __syncthreads();
    {
        int r = tid >> 6, c = tid & 63;
        int ox = x0d + c;
        #pragma unroll
        for (int j = 0; j < 4; ++j) {
            int oy = y0d + r*4 + j;
            int rb = 2*(r*4 + j);
            float s = 0.f;
            #pragma unroll
            for (int k = 0; k < 9; ++k) s = fmaf(g.w[k], mid[rb + k][c], s);
            T1[out_off + (size_t)oy * Wd + ox] = s;
        }
    }
}

// ---------------------------------------------------------------------------
// dev_M: fused [z-filter+subsample+batch-mix of Tin -> C tile in LDS, interior
// written to global C] then [W+H filter+subsample -> Tout]. One block per
// (batch, z-out, y-tile of 16 downsampled rows); whole-x tiles (Wp <= 128).
struct MP {
    const float* Tin; float* C; float* Tout;
    int Dz, Dc, Hp, Wp, nty, writeT, nM;
};

__device__ void dev_M(int m, const MP& mp, const GW& g, float* smem)
{
    float* raw = smem;             // [40][136]
    float* mid = smem + 40*136;    // [40][64]
    const int tid = threadIdx.x;
    const int ytile = m % mp.nty;
    const int zidx  = m / mp.nty;
    const int b  = zidx / mp.Dc;
    const int zc = zidx - b * mp.Dc;
    const int Dz = mp.Dz, Hp = mp.Hp, Wp = mp.Wp;
    const int Hd = Hp >> 1, Wd = Wp >> 1;
    const int y0d = ytile * 16;
    const int CC = (Wp + 8 > 136) ? 136 : (Wp + 8);
    const size_t plane = (size_t)Hp * Wp;
    // stage: z-filter (9 taps, both batches) + batch-mix; own-write C interior
    for (int i = tid; i < 40*CC; i += 256) {
        int rr = i / CC, cc = i - rr*CC;
        int gy = ridx(2*y0d - 4 + rr, Hp);
        int gx = ridx(cc - 4, Wp);
        size_t base = (size_t)gy * Wp + gx;
        float s0 = 0.f, s1 = 0.f;
        #pragma unroll
        for (int k = 0; k < 9; ++k) {
            int zt = ridx(2*zc - 4 + k, Dz);
            s0 = fmaf(g.w[k], mp.Tin[(size_t)zt * plane + base], s0);
            s1 = fmaf(g.w[k], mp.Tin[(size_t)(Dz + zt) * plane + base], s1);
        }
        float val = (b == 0) ? (g.A*s0 + g.B*s1) : (g.B*s0 + g.A*s1);
        raw[rr*136 + cc] = val;
        int gyo = 2*y0d + rr - 4;
        if (rr >= 4 && rr < 36 && gyo < Hp && cc >= 4 && cc < 4 + Wp) {
            mp.C[((size_t)(b*mp.Dc + zc) * Hp + gyo) * Wp + (cc - 4)] = val;
        }
    }
    if (!mp.writeT) return;        // uniform per block; no divergent barrier
    __syncthreads();
    for (int i = tid; i < 40*64; i += 256) {
        int rr = i >> 6, c = i & 63;
        float s = 0.f;
        #pragma unroll
        for (int k = 0; k < 9; ++k) s = fmaf(g.w[k], raw[rr*136 + 2*c + k], s);
        mid[rr*64 + c] = s;
    }
    __syncthreads();
    {
        int r = tid >> 6, c = tid & 63;
        #pragma unroll
        for (int j = 0; j < 4; ++j) {
            int oy = y0d + r*4 + j;
            if (oy < Hd && c < Wd) {
                int rb = 2*(r*4 + j);
                float s = 0.f;
                #pragma unroll
                for (int k = 0; k < 9; ++k) s = fmaf(g.w[k], mid[(rb+k)*64 + c], s);
                mp.Tout[((size_t)(b*mp.Dc + zc) * Hd + oy) * Wd + c] = s;
            }
        }
    }
}

// ---------------------------------------------------------------------------
// dev_k3_elem: D-filter of zero-stuffed dn + batch mix (upsample D/batch), x8.
struct K3 { const float* dn; float* V; int D, Dd, M4, n; };

__device__ void dev_k3_elem(long i, const K3& kp, const GW& g)
{
    const float4* Dn = (const float4*)kp.dn;
    float4* O = (float4*)kp.V;
    const int D = kp.D, Dd = kp.Dd, M4 = kp.M4;
    if (i >= (long)D * M4) return;
    int z = (int)(i / M4);
    int q = (int)(i - (long)z * M4);
    float4 s0 = {0,0,0,0}, s1 = {0,0,0,0};
    auto f4 = [](float4& a, float w, const float4 b) {
        a.x = fmaf(w, b.x, a.x); a.y = fmaf(w, b.y, a.y);
        a.z = fmaf(w, b.z, a.z); a.w = fmaf(w, b.w, a.w);
    };
    if (z >= 4 && z + 4 < D) {
        if ((z & 1) == 0) {
            int base = (z >> 1) - 2;
            #pragma unroll
            for (int kk = 0; kk < 5; ++kk) {
                f4(s0, g.w[2*kk], Dn[(size_t)(base + kk) * M4 + q]);
                f4(s1, g.w[2*kk], Dn[(size_t)(Dd + base + kk) * M4 + q]);
            }
        } else {
            int base = (z - 3) >> 1;
            #pragma unroll
            for (int kk = 0; kk < 4; ++kk) {
                f4(s0, g.w[2*kk+1], Dn[(size_t)(base + kk) * M4 + q]);
                f4(s1, g.w[2*kk+1], Dn[(size_t)(Dd + base + kk) * M4 + q]);
            }
        }
    } else {
        #pragma unroll
        for (int k = 0; k < 9; ++k) {
            int zk = ridx(z - 4 + k, D);
            if (!(zk & 1)) {
                int j = zk >> 1;
                f4(s0, g.w[k], Dn[(size_t)j * M4 + q]);
                f4(s1, g.w[k], Dn[(size_t)(Dd + j) * M4 + q]);
            }
        }
    }
    float4 o0, o1;
    o0.x = 8.f*(g.A*s0.x + g.B*s1.x); o0.y = 8.f*(g.A*s0.y + g.B*s1.y);
    o0.z = 8.f*(g.A*s0.z + g.B*s1.z); o0.w = 8.f*(g.A*s0.w + g.B*s1.w);
    o1.x = 8.f*(g.B*s0.x + g.A*s1.x); o1.y = 8.f*(g.B*s0.y + g.A*s1.y);
    o1.z = 8.f*(g.B*s0.z + g.A*s1.z); o1.w = 8.f*(g.B*s0.w + g.A*s1.w);
    O[(size_t)z * M4 + q] = o0;
    O[(size_t)(D + z) * M4 + q] = o1;
}

// ---------------------------------------------------------------------------
// dev_k4: loss tile (proven r10 form). gbid = global k4 index over all levels.
// Levels 0-2: stage vt from materialized V; levels 3-4: fused generic-z from dn.
struct K4P {
    const float* V[3];
    const float* dn34[2];   // C4, C5
    const float* cur[5];    // cur[1..4] = C1..C4
    const float* in; const float* tg;
    const __hip_bfloat16* DIFF;
    float* P;
    int use_diff;
    int bo[6];
    GW g;
};

__device__ void dev_k4(int gbid, const K4P& p, float* smem)
{
    const int Dt[5] = {64,32,16,8,4}, Ht[5] = {256,128,64,32,16};
    float* vt  = smem;            // [20][72]
    float* mid = smem + 20*72;    // [20][64]
    int l = 0;
    while (l < 4 && gbid >= p.bo[l+1]) ++l;
    const int local = gbid - p.bo[l];
    const int D = Dt[l], H = Ht[l], W = H;
    const int Dd = D >> 1, Hd = H >> 1, Wd = W >> 1, Md = Hd * Wd;
    const int ntx = (l == 0) ? 3 : ((W + 63) >> 6);
    const int nty = (H + 31) >> 5;
    const int s = local / (ntx*nty);
    const int rem = local - s*(ntx*nty);
    const int ty = rem / ntx, tx = rem - ty*ntx;
    const int x0 = tx*64, y0 = ty*32;
    const int b = s / D, z = s - b*D;
    const GW g = p.g;
    const int tid = threadIdx.x;
    const int vy0 = (y0 >> 1) - 2;

    if (l < 3) {
        const float* V = p.V[l];
        const size_t v_off = (size_t)s * Md;
        for (int i = tid; i < 20*72; i += 256) {
            int rr = i / 72, cc = i - rr*72;
            int vy = vy0 + rr;
            int txx = x0 - 4 + cc;
            if (txx < 0) txx = -1 - txx;
            float v = 0.f;
            if (vy >= 0 && vy < Hd && txx < Wd) v = V[v_off + (size_t)vy * Wd + txx];
            vt[rr*72 + cc] = v;
        }
    } else {
        const float* dnb = p.dn34[l-3];
        const float* dn0 = dnb + (size_t)b * Dd * Md;
        const float* dn1 = dnb + (size_t)(1 - b) * Dd * Md;
        for (int i = tid; i < 20*72; i += 256) {
            int rr = i / 72, cc = i - rr*72;
            int vy = vy0 + rr;
            int txx = x0 - 4 + cc;
            if (txx < 0) txx = -1 - txx;
            float v = 0.f;
            if (vy >= 0 && vy < Hd && txx < Wd) {
                size_t o = (size_t)vy * Wd + txx;
                float s0 = 0.f, s1 = 0.f;
                #pragma unroll
                for (int k = 0; k < 9; ++k) {
                    int zk = ridx(z - 4 + k, D);
                    if (!(zk & 1)) {
                        int j = zk >> 1;
                        s0 = fmaf(g.w[k], dn0[(size_t)j * Md + o], s0);
                        s1 = fmaf(g.w[k], dn1[(size_t)j * Md + o], s1);
                    }
                }
                v = 8.f * (g.A*s0 + g.B*s1);
            }
            vt[rr*72 + cc] = v;
        }
    }
    __syncthreads();
    for (int i = tid; i < 20*64; i += 256) {
        int rr = i >> 6, c = i & 63;
        float sv = 0.f;
        #pragma unroll
        for (int k = 0; k < 9; ++k) sv = fmaf(g.w[k], vt[rr*72 + c + k], sv);
        mid[rr*64 + c] = sv;
    }
    __syncthreads();
    const bool yin = (y0 >= 4) && (y0 + 35 < H);
    const int c = tid & 63;
    const int ry_base = (tid >> 6) * 8;
    const int ox = x0 + c;
    const int xlim = (l == 0) ? 132 : W;
    const size_t c_off = (size_t)s * H * W;
    const float* curl = (l >= 1) ? p.cur[l] : nullptr;
    float lsum = 0.f;
    #pragma unroll
    for (int j = 0; j < 8; ++j) {
        int ry = ry_base + j;
        int oy = y0 + ry;
        if (ox < xlim && oy < H) {
            float sv = 0.f;
            if (yin) {
                if (!(j & 1)) {
                    int r0 = ry >> 1;
                    sv = g.w[0]*mid[r0*64+c] + g.w[2]*mid[(r0+1)*64+c]
                       + g.w[4]*mid[(r0+2)*64+c] + g.w[6]*mid[(r0+3)*64+c]
                       + g.w[8]*mid[(r0+4)*64+c];
                } else {
                    int r0 = ((ry - 3) >> 1) + 2;
                    sv = g.w[1]*mid[r0*64+c] + g.w[3]*mid[(r0+1)*64+c]
                       + g.w[5]*mid[(r0+2)*64+c] + g.w[7]*mid[(r0+3)*64+c];
                }
            } else {
                #pragma unroll
                for (int k = 0; k < 9; ++k) {
                    int gy = ridx(oy - 4 + k, H);
                    if (!(gy & 1)) sv = fmaf(g.w[k], mid[((gy >> 1) - vy0)*64 + c], sv);
                }
            }
            size_t idx = c_off + (size_t)oy * W + ox;
            float cv;
            if (l == 0) cv = p.use_diff ? __bfloat162float(p.DIFF[idx])
                                        : (p.in[idx] - p.tg[idx]);
            else        cv = curl[idx];
            lsum += fabsf(cv - sv);
        }
    }
    float tot = block_sum256(lsum);
    if (tid == 0) p.P[1024 + gbid] = tot / ((float)(2*D) * H * W);
}

// ------------------------------- kernels -----------------------------------
__global__ __launch_bounds__(256)
void kM1(MP mp, GW g)
{
    __shared__ float smem[40*136 + 40*64];
    dev_M((int)blockIdx.x, mp, g, smem);
}

// D3: M2 || k3(0)
__global__ __launch_bounds__(256)
void kD3(MP mp, K3 k3, GW g)
{
    __shared__ float smem[40*136 + 40*64];
    int bid = (int)blockIdx.x;
    if (bid < mp.nM) dev_M(bid, mp, g, smem);
    else dev_k3_elem((long)(bid - mp.nM)*256 + threadIdx.x, k3, g);
}

// D4/D5: M || k3 || k4 (k4 global index = bid0 + local)
__global__ __launch_bounds__(256)
void kD45(MP mp, K3 k3, K4P k4, int bid0, GW g)
{
    __shared__ float smem[40*136 + 40*64];
    int bid = (int)blockIdx.x;
    if (bid < mp.nM) dev_M(bid, mp, g, smem);
    else if (bid < mp.nM + k3.n)
        dev_k3_elem((long)(bid - mp.nM)*256 + threadIdx.x, k3, g);
    else dev_k4(bid0 + (bid - mp.nM - k3.n), k4, smem);
}

// D6: M5 || k4-L2
__global__ __launch_bounds__(256)
void kD6(MP mp, K4P k4, int bid0, GW g)
{
    __shared__ float smem[40*136 + 40*64];
    int bid = (int)blockIdx.x;
    if (bid < mp.nM) dev_M(bid, mp, g, smem);
    else dev_k4(bid0 + (bid - mp.nM), k4, smem);
}

// D7: k4-L3 || k4-L4
__global__ __launch_bounds__(256)
void kD7(K4P k4, int bid0)
{
    __shared__ float smem[20*72 + 20*64];
    dev_k4(bid0 + (int)blockIdx.x, k4, smem);
}

__global__ __launch_bounds__(1024)
void kreduce(const float* __restrict__ P, int n, float* __restrict__ out)
{
    float s = 0.f;
    for (int i = threadIdx.x; i < n; i += 1024) s += P[i];
    #pragma unroll
    for (int off = 32; off > 0; off >>= 1) s += __shfl_down(s, off, 64);
    __shared__ float wp[16];
    if ((threadIdx.x & 63) == 0) wp[threadIdx.x >> 6] = s;
    __syncthreads();
    if (threadIdx.x == 0) {
        float t = 0.f;
        #pragma unroll
        for (int w = 0; w < 16; ++w) t += wp[w];
        out[0] = t;
    }
}

// ---------------------------------------------------------------------------
extern "C" void kernel_launch(void* const* d_in, const int* in_sizes, int n_in,
                              void* d_out, int out_size, void* d_ws, size_t ws_size,
                              hipStream_t stream)
{
    const float* in = (const float*)d_in[0];
    const float* tg = (const float*)d_in[1];
    float* out = (float*)d_out;

    GW g;
    {
        double u[9], S = 0.0;
        for (int k = 0; k < 9; ++k) { double d = k - 4; u[k] = exp(-0.5 * d * d); S += u[k]; }
        for (int k = 0; k < 9; ++k) g.w[k] = (float)(u[k] / S);
        g.A = (float)((2.0*u[0] + u[1] + u[3] + u[4]) / S);  // batch(2) reflect self-weight
        g.B = (float)((u[1] + 2.0*u[2] + u[3]) / S);         // cross-weight
    }

    // workspace layout (floats)
    float* T1  = (float*)d_ws;             // 2*64*128*128 = 2097152
    float* C1  = T1  + 2097152;            // 1048576
    float* C2  = C1  + 1048576;            // 131072
    float* C3  = C2  + 131072;             // 16384
    float* C4  = C3  + 16384;              // 2048
    float* C5  = C4  + 2048;               // 256
    float* Tl1 = C5  + 256;                // 2*32*64*64 = 262144
    float* Tl2 = Tl1 + 262144;             // 2*16*32*32 = 32768
    float* Tl3 = Tl2 + 32768;              // 2*8*16*16  = 4096
    float* Tl4 = Tl3 + 4096;               // 2*4*8*8    = 512
    float* V0  = Tl4 + 512;                // 2*64*128*128 = 2097152
    float* V1  = V0  + 2097152;            // 2*32*64*64   = 262144
    float* V2  = V1  + 262144;             // 2*16*32*32   = 32768
    float* P   = V2  + 32768;              // 1024 + 3672 partials
    float* wend = P + 8192;
    __hip_bfloat16* DIFF = (__hip_bfloat16*)wend;
    const size_t base_bytes = (size_t)((char*)wend - (char*)d_ws);
    const size_t diff_bytes = (size_t)2 * 64 * 256 * 256 * sizeof(__hip_bfloat16);
    const int use_diff = (ws_size >= base_bytes + diff_bytes) ? 1 : 0;

    dim3 blk(256);

    // shared param structs
    K4P k4;
    k4.V[0] = V0; k4.V[1] = V1; k4.V[2] = V2;
    k4.dn34[0] = C4; k4.dn34[1] = C5;
    k4.cur[0] = nullptr; k4.cur[1] = C1; k4.cur[2] = C2; k4.cur[3] = C3; k4.cur[4] = C4;
    k4.in = in; k4.tg = tg;
    k4.DIFF = use_diff ? DIFF : nullptr;
    k4.P = P; k4.use_diff = use_diff;
    k4.g = g;
    k4.bo[0] = 0; k4.bo[1] = 3072; k4.bo[2] = 3584;
    k4.bo[3] = 3648; k4.bo[4] = 3664; k4.bo[5] = 3672;

    // D1: level-0 WH-down of diff (+ bf16 DIFF x<132, + x>=132 partials)
    if (use_diff) k1l0<true ><<<dim3(2,8,128), blk, 0, stream>>>(in, tg, T1, DIFF, P, g);
    else          k1l0<false><<<dim3(2,8,128), blk, 0, stream>>>(in, tg, T1, nullptr, P, g);

    // D2: M1: T1 (2,64,128,128) -> C1 + Tl1 (2,32,64,64). nty=4, nM=256.
    {
        MP mp; mp.Tin = T1; mp.C = C1; mp.Tout = Tl1;
        mp.Dz = 64; mp.Dc = 32; mp.Hp = 128; mp.Wp = 128; mp.nty = 4; mp.writeT = 1;
        mp.nM = 256;
        kM1<<<dim3(256), blk, 0, stream>>>(mp, g);
    }
    // D3: M2 (Tl1 -> C2 + Tl2, nM=64) || k3(0): C1 -> V0 (1024 blocks)
    {
        MP mp; mp.Tin = Tl1; mp.C = C2; mp.Tout = Tl2;
        mp.Dz = 32; mp.Dc = 16; mp.Hp = 64; mp.Wp = 64; mp.nty = 2; mp.writeT = 1;
        mp.nM = 64;
        K3 k3 = { C1, V0, 64, 32, 4096, 1024 };
        kD3<<<dim3(64 + 1024), blk, 0, stream>>>(mp, k3, g);
    }
    // D4: M3 (Tl2 -> C3 + Tl3, nM=16) || k3(1): C2 -> V1 (128) || k4-L0 (3072)
    {
        MP mp; mp.Tin = Tl2; mp.C = C3; mp.Tout = Tl3;
        mp.Dz = 16; mp.Dc = 8; mp.Hp = 32; mp.Wp = 32; mp.nty = 1; mp.writeT = 1;
        mp.nM = 16;
        K3 k3 = { C2, V1, 32, 16, 1024, 128 };
        kD45<<<dim3(16 + 128 + 3072), blk, 0, stream>>>(mp, k3, k4, 0, g);
    }
    // D5: M4 (Tl3 -> C4 + Tl4, nM=8) || k3(2): C3 -> V2 (16) || k4-L1 (512)
    {
        MP mp; mp.Tin = Tl3; mp.C = C4; mp.Tout = Tl4;
        mp.Dz = 8; mp.Dc = 4; mp.Hp = 16; mp.Wp = 16; mp.nty = 1; mp.writeT = 1;
        mp.nM = 8;
        K3 k3 = { C3, V2, 16, 8, 256, 16 };
        kD45<<<dim3(8 + 16 + 512), blk, 0, stream>>>(mp, k3, k4, 3072, g);
    }
    // D6: M5 (Tl4 -> C5, no Tout, nM=4) || k4-L2 (64)
    {
        MP mp; mp.Tin = Tl4; mp.C = C5; mp.Tout = nullptr;
        mp.Dz = 4; mp.Dc = 2; mp.Hp = 8; mp.Wp = 8; mp.nty = 1; mp.writeT = 0;
        mp.nM = 4;
        kD6<<<dim3(4 + 64), blk, 0, stream>>>(mp, k4, 3584, g);
    }
    // D7: k4-L3 (16) || k4-L4 (8)
    kD7<<<dim3(24), blk, 0, stream>>>(k4, 3648);

    // D8: final reduce over 1024 + 3672 partials
    kreduce<<<1, 1024, 0, stream>>>(P, 1024 + 3672, out);
}